// Round 8
// baseline (3783.820 us; speedup 1.0000x reference)
//
#include <hip/hip_runtime.h>

#define NBLK 64
#define NTHR 256
#define SEQ  512
#define BAT  64
#define NINP 256
#define NHID 512
#define LDG  2048   // 4*NHID
#define GOLD 0x9E3779B9u

typedef __attribute__((ext_vector_type(8))) short short8;
typedef __attribute__((ext_vector_type(4))) float f32x4;
typedef __attribute__((ext_vector_type(4))) unsigned int uint4v;

static __device__ __forceinline__ unsigned short f2bf(float x) {
    return __builtin_bit_cast(unsigned short, (__bf16)x);
}
static __device__ __forceinline__ float sigm(float x)  { return 1.0f / (1.0f + __expf(-x)); }
static __device__ __forceinline__ float tanh_(float x) { return 2.0f / (1.0f + __expf(-2.0f * x)) - 1.0f; }

// L3-coherent 16B ops (bypass L1/L2), no implicit wait.
static __device__ __forceinline__ void cload(uint4v& d, const uint4v* p) {
    asm volatile("global_load_dwordx4 %0, %1, off sc0 sc1" : "=v"(d) : "v"(p) : "memory");
}
static __device__ __forceinline__ void cstore(uint4v v, uint4v* p) {
    asm volatile("global_store_dwordx4 %0, %1, off sc0 sc1" :: "v"(p), "v"(v) : "memory");
}

// d_ws: [0, 256KB) h chunk buffer, [256KB, +1KB) flags (256 = one per (block,wave)).
// Chunk (16B) = {d0,d1: 4 bf16 h, tag = t+1, ck = d0+d1+(t+1)*GOLD}.
// Chunk index: ((slot*NBLK + prodBlk)*BAT + row)*2 + half.
// Protocol: producer fires 2 chunk stores/lane + flag store with NO ack wait;
// consumer: small flag poll (detect) -> one-shot chunk load -> checksum validate
// (catches data-vs-flag completion skew; retry is rare).
__global__ __launch_bounds__(NTHR, 1)
void lstm_persistent(const float* __restrict__ x, const float* __restrict__ W,
                     const float* __restrict__ U, const float* __restrict__ bias,
                     float* __restrict__ out, uint4v* __restrict__ hbuf,
                     unsigned int* __restrict__ flags)
{
    __shared__ short8 lds_s[4 * 16];   // per-wave 256B transpose staging (wave-private)

    const int bk   = blockIdx.x;
    const int tid  = threadIdx.x;
    const int w    = tid >> 6;
    const int lane = tid & 63;
    const int c16  = lane & 15;
    const int rq   = lane >> 4;

    const int col0 = (c16 >> 3) * NHID + (c16 & 7) + bk * 8;   // i (c16<8) or f
    const int col1 = col0 + 2 * NHID;                           // g or o

    // ---- one-time: U,W slices into register B-fragments ----
    short8 ut[2][16];
#pragma unroll
    for (int kb = 0; kb < 16; ++kb) {
        const int k0 = kb * 32 + rq * 8;
        short8 v0, v1;
#pragma unroll
        for (int j = 0; j < 8; ++j) {
            v0[j] = (short)f2bf(U[(size_t)(k0 + j) * LDG + col0]);
            v1[j] = (short)f2bf(U[(size_t)(k0 + j) * LDG + col1]);
        }
        ut[0][kb] = v0; ut[1][kb] = v1;
    }
    short8 wt[2][8];
#pragma unroll
    for (int kb = 0; kb < 8; ++kb) {
        const int k0 = kb * 32 + rq * 8;
        short8 v0, v1;
#pragma unroll
        for (int j = 0; j < 8; ++j) {
            v0[j] = (short)f2bf(W[(size_t)(k0 + j) * LDG + col0]);
            v1[j] = (short)f2bf(W[(size_t)(k0 + j) * LDG + col1]);
        }
        wt[0][kb] = v0; wt[1][kb] = v1;
    }
    const float bias0 = bias[col0];
    const float bias1 = bias[col1];

    const int  arow  = w * 16 + c16;
    const bool lower = (c16 < 8);
    const bool up    = (c16 & 8);
    const int  hcol  = bk * 8 + (c16 & 7);
    float cst[4] = {0.f, 0.f, 0.f, 0.f};

    float* hout  = out + (size_t)SEQ * BAT * NHID;
    float* cout_ = hout + BAT * NHID;

    unsigned short* lds_w = (unsigned short*)&lds_s[w * 16];

    // ---- prologue: prefetch+convert x(0) fragments (plain loads, compiler-managed) ----
    short8 xan[8];
    {
        const float* xr = x + (size_t)arow * NINP + rq * 8;
#pragma unroll
        for (int kb = 0; kb < 8; ++kb) {
            f32x4 a0 = *(const f32x4*)(xr + kb * 32);
            f32x4 a1 = *(const f32x4*)(xr + kb * 32 + 4);
            short8 v;
#pragma unroll
            for (int j = 0; j < 4; ++j) {
                v[j]     = (short)f2bf(a0[j]);
                v[j + 4] = (short)f2bf(a1[j]);
            }
            xan[kb] = v;
        }
    }

    for (int t = 0; t < SEQ; ++t) {
        const int pR = (t + 1) & 1;   // slot holding h(t-1)
        const int pW = t & 1;         // slot receiving h(t)

        // ---------- x @ W from prefetched fragments (register-only) ----------
        f32x4 acc[2][4];
#pragma unroll
        for (int nt = 0; nt < 2; ++nt)
#pragma unroll
            for (int ch = 0; ch < 4; ++ch) acc[nt][ch] = (f32x4){0.f, 0.f, 0.f, 0.f};
#pragma unroll
        for (int kb = 0; kb < 8; ++kb) {
            const int ch = kb & 3;
            acc[0][ch] = __builtin_amdgcn_mfma_f32_16x16x32_bf16(xan[kb], wt[0][kb], acc[0][ch], 0, 0, 0);
            acc[1][ch] = __builtin_amdgcn_mfma_f32_16x16x32_bf16(xan[kb], wt[1][kb], acc[1][ch], 0, 0, 0);
        }

        if (t > 0) {
            // ---------- detect: small flag poll (16B/lane), then release block ----------
            if (tid < NBLK) {
                const unsigned int* fp = flags + tid * 4;
                uint4v f;
                do {
                    asm volatile("global_load_dwordx4 %0, %1, off sc0 sc1\n\t"
                                 "s_waitcnt vmcnt(0)"
                                 : "=v"(f) : "v"(fp) : "memory");
                } while (f[0] < (unsigned)t || f[1] < (unsigned)t ||
                         f[2] < (unsigned)t || f[3] < (unsigned)t);
            }
            __syncthreads();

            // ---------- one-shot chunk load + validate (retry only on store skew) ----------
            const uint4v* base = hbuf + ((size_t)pR * NBLK * BAT + arow) * 2;
            const unsigned tagv = (unsigned)t;
            const unsigned ckt  = tagv * GOLD;
            uint4v chnk[32];
            for (;;) {
#pragma unroll
                for (int kb = 0; kb < 16; ++kb) {
                    const uint4v* cp = base + (size_t)(kb * 4 + rq) * (BAT * 2);
                    cload(chnk[2 * kb],     cp);
                    cload(chnk[2 * kb + 1], cp + 1);
                }
                asm volatile("s_waitcnt vmcnt(0)" ::: "memory");
                __builtin_amdgcn_sched_barrier(0);
                bool ok = true;
#pragma unroll
                for (int i = 0; i < 32; ++i)
                    ok = ok && (chnk[i].z == tagv) &&
                         (chnk[i].w == chnk[i].x + chnk[i].y + ckt);
                if (__all(ok)) break;
            }
            __builtin_amdgcn_sched_barrier(0);

            // ---------- h @ U ----------
#pragma unroll
            for (int kb = 0; kb < 16; ++kb) {
                union { uint4v u; short8 s; } a;
                a.u = (uint4v){chnk[2 * kb].x,     chnk[2 * kb].y,
                               chnk[2 * kb + 1].x, chnk[2 * kb + 1].y};
                const int ch = kb & 3;
                acc[0][ch] = __builtin_amdgcn_mfma_f32_16x16x32_bf16(a.s, ut[0][kb], acc[0][ch], 0, 0, 0);
                acc[1][ch] = __builtin_amdgcn_mfma_f32_16x16x32_bf16(a.s, ut[1][kb], acc[1][ch], 0, 0, 0);
            }
        }
        // t == 0: h(-1) = 0, h@U contributes nothing -> skipped entirely.

        f32x4 gif = acc[0][0] + acc[0][1] + acc[0][2] + acc[0][3];
        f32x4 ggo = acc[1][0] + acc[1][1] + acc[1][2] + acc[1][3];
#pragma unroll
        for (int j = 0; j < 4; ++j) { gif[j] += bias0; ggo[j] += bias1; }

        // ---- gate exchange + nonlinearity ----
        f32x4 oif, ogo;
#pragma unroll
        for (int j = 0; j < 4; ++j) {
            oif[j] = __shfl_xor(gif[j], 8, 64);
            ogo[j] = __shfl_xor(ggo[j], 8, 64);
        }
        float hv[4];
#pragma unroll
        for (int j = 0; j < 4; ++j) {
            const float gi = up ? oif[j] : gif[j];
            const float gf = up ? gif[j] : oif[j];
            const float gg = up ? ogo[j] : ggo[j];
            const float go = up ? ggo[j] : ogo[j];
            const float iv = sigm(gi);
            const float fv = sigm(gf);
            const float gv = tanh_(gg);
            const float ov = sigm(go);
            const float cn = fv * cst[j] + iv * gv;
            cst[j] = cn;
            hv[j] = ov * tanh_(cn);
        }

        // ---------- publish h(t): fire chunks, then flag — NO ack wait ----------
        if (t < SEQ - 1) {
            if (lower) {
#pragma unroll
                for (int j = 0; j < 4; ++j)
                    lds_w[(rq * 4 + j) * 8 + c16] = f2bf(hv[j]);
            }
            __builtin_amdgcn_sched_barrier(0);
            if (lane < 32) {
                const int row  = lane >> 1;      // 0..15 within wave
                const int half = lane & 1;       // which 4 cols
                const unsigned int* lp = (const unsigned int*)(lds_w + row * 8 + half * 4);
                const unsigned d0 = lp[0], d1 = lp[1];   // compiler inserts lgkmcnt
                const unsigned tg = (unsigned)(t + 1);
                uint4v c;
                c.x = d0; c.y = d1; c.z = tg; c.w = d0 + d1 + tg * GOLD;
                cstore(c, hbuf + ((size_t)(pW * NBLK + bk) * BAT + (w * 16 + row)) * 2 + half);
            }
            if (lane == 0) {
                unsigned int* fp2 = flags + bk * 4 + w;
                unsigned int val = (unsigned)(t + 1);
                asm volatile("global_store_dword %0, %1, off sc0 sc1"
                             :: "v"(fp2), "v"(val) : "memory");
            }
        }

        // ---------- output stores (off the critical path) ----------
        if (lower) {
#pragma unroll
            for (int j = 0; j < 4; ++j) {
                const int batch = w * 16 + rq * 4 + j;
                out[((size_t)t * BAT + batch) * NHID + hcol] = hv[j];
                if (t == SEQ - 1) {
                    hout[batch * NHID + hcol]  = hv[j];
                    cout_[batch * NHID + hcol] = cst[j];
                }
            }
        }

        // ---------- prefetch + convert x(t+1) (waits hide under next poll) ----------
        if (t < SEQ - 1) {
            const float* xr = x + ((size_t)(t + 1) * BAT + arow) * NINP + rq * 8;
#pragma unroll
            for (int kb = 0; kb < 8; ++kb) {
                f32x4 a0 = *(const f32x4*)(xr + kb * 32);
                f32x4 a1 = *(const f32x4*)(xr + kb * 32 + 4);
                short8 v;
#pragma unroll
                for (int j = 0; j < 4; ++j) {
                    v[j]     = (short)f2bf(a0[j]);
                    v[j + 4] = (short)f2bf(a1[j]);
                }
                xan[kb] = v;
            }
        }
    }
}

extern "C" void kernel_launch(void* const* d_in, const int* in_sizes, int n_in,
                              void* d_out, int out_size, void* d_ws, size_t ws_size,
                              hipStream_t stream) {
    (void)in_sizes; (void)n_in; (void)out_size; (void)ws_size;
    const float* x  = (const float*)d_in[0];
    const float* W  = (const float*)d_in[1];
    const float* U  = (const float*)d_in[2];
    const float* b  = (const float*)d_in[3];
    float* out = (float*)d_out;

    uint4v*       hbuf  = (uint4v*)d_ws;
    unsigned int* flags = (unsigned int*)((char*)d_ws + 262144);

    // Zero chunk tags + flags every launch (stale data can never false-match).
    hipMemsetAsync(d_ws, 0, 262144 + 4096, stream);
    hipLaunchKernelGGL(lstm_persistent, dim3(NBLK), dim3(NTHR), 0, stream,
                       x, W, U, b, out, hbuf, flags);
}

// Round 11
// 3024.245 us; speedup vs baseline: 1.2512x; 1.2512x over previous
//
#include <hip/hip_runtime.h>

#define NBLK 64
#define NTHR 256
#define SEQ  512
#define BAT  64
#define NINP 256
#define NHID 512
#define LDG  2048   // 4*NHID

typedef __attribute__((ext_vector_type(8))) short short8;
typedef __attribute__((ext_vector_type(4))) float f32x4;
typedef __attribute__((ext_vector_type(4))) unsigned int uint4v;

static __device__ __forceinline__ unsigned short f2bf(float x) {
    return __builtin_bit_cast(unsigned short, (__bf16)x);
}
static __device__ __forceinline__ float sigm(float x)  { return 1.0f / (1.0f + __expf(-x)); }
static __device__ __forceinline__ float tanh_(float x) { return 2.0f / (1.0f + __expf(-2.0f * x)) - 1.0f; }

// L3-coherent 16B load, no implicit wait (caller drains vmcnt explicitly).
static __device__ __forceinline__ void hload(short8& d, const unsigned short* p) {
    asm volatile("global_load_dwordx4 %0, %1, off sc0 sc1" : "=v"(d) : "v"(p) : "memory");
}
// L3-coherent 16B store.
static __device__ __forceinline__ void hstore16(short8 v, unsigned short* p) {
    asm volatile("global_store_dwordx4 %0, %1, off sc0 sc1" :: "v"(p), "v"(v) : "memory");
}

// d_ws: [0,1KB) flags (256 uints, one per (block,wave)),
//       [4KB,4KB+2*64KB) h double buffer, block-major: [parity][block][batch][8 cols] bf16.
__global__ __launch_bounds__(NTHR, 1)
void lstm_persistent(const float* __restrict__ x, const float* __restrict__ W,
                     const float* __restrict__ U, const float* __restrict__ bias,
                     float* __restrict__ out, unsigned short* __restrict__ hbuf,
                     unsigned int* __restrict__ flags)
{
    __shared__ short8 lds_s[4 * 16];   // per-wave 256B transpose staging (wave-private)

    const int bk   = blockIdx.x;
    const int tid  = threadIdx.x;
    const int w    = tid >> 6;
    const int lane = tid & 63;
    const int c16  = lane & 15;
    const int rq   = lane >> 4;

    const int col0 = (c16 >> 3) * NHID + (c16 & 7) + bk * 8;   // i (c16<8) or f
    const int col1 = col0 + 2 * NHID;                           // g or o

    // ---- one-time: U,W slices into register B-fragments ----
    short8 ut[2][16];
#pragma unroll
    for (int kb = 0; kb < 16; ++kb) {
        const int k0 = kb * 32 + rq * 8;
        short8 v0, v1;
#pragma unroll
        for (int j = 0; j < 8; ++j) {
            v0[j] = (short)f2bf(U[(size_t)(k0 + j) * LDG + col0]);
            v1[j] = (short)f2bf(U[(size_t)(k0 + j) * LDG + col1]);
        }
        ut[0][kb] = v0; ut[1][kb] = v1;
    }
    short8 wt[2][8];
#pragma unroll
    for (int kb = 0; kb < 8; ++kb) {
        const int k0 = kb * 32 + rq * 8;
        short8 v0, v1;
#pragma unroll
        for (int j = 0; j < 8; ++j) {
            v0[j] = (short)f2bf(W[(size_t)(k0 + j) * LDG + col0]);
            v1[j] = (short)f2bf(W[(size_t)(k0 + j) * LDG + col1]);
        }
        wt[0][kb] = v0; wt[1][kb] = v1;
    }
    const float bias0 = bias[col0];
    const float bias1 = bias[col1];

    const int  arow  = w * 16 + c16;
    const bool lower = (c16 < 8);
    const bool up    = (c16 & 8);
    const int  hcol  = bk * 8 + (c16 & 7);
    float cst[4] = {0.f, 0.f, 0.f, 0.f};

    float* hout  = out + (size_t)SEQ * BAT * NHID;
    float* cout_ = hout + BAT * NHID;

    unsigned short* lds_w = (unsigned short*)&lds_s[w * 16];

    // ---- prologue: prefetch + convert x(0) fragments (plain loads) ----
    short8 xan[8];
    {
        const float* xr = x + (size_t)arow * NINP + rq * 8;
#pragma unroll
        for (int kb = 0; kb < 8; ++kb) {
            f32x4 a0 = *(const f32x4*)(xr + kb * 32);
            f32x4 a1 = *(const f32x4*)(xr + kb * 32 + 4);
            short8 v;
#pragma unroll
            for (int j = 0; j < 4; ++j) {
                v[j]     = (short)f2bf(a0[j]);
                v[j + 4] = (short)f2bf(a1[j]);
            }
            xan[kb] = v;
        }
    }

    for (int t = 0; t < SEQ; ++t) {
        const int pR = (t + 1) & 1;   // parity to read (h(t-1))
        const int pW = t & 1;         // parity to write (h(t))

        // ---------- x @ W from prefetched register fragments ----------
        f32x4 acc[2][4];
#pragma unroll
        for (int nt = 0; nt < 2; ++nt)
#pragma unroll
            for (int ch = 0; ch < 4; ++ch) acc[nt][ch] = (f32x4){0.f, 0.f, 0.f, 0.f};
#pragma unroll
        for (int kb = 0; kb < 8; ++kb) {
            const int ch = kb & 3;
            acc[0][ch] = __builtin_amdgcn_mfma_f32_16x16x32_bf16(xan[kb], wt[0][kb], acc[0][ch], 0, 0, 0);
            acc[1][ch] = __builtin_amdgcn_mfma_f32_16x16x32_bf16(xan[kb], wt[1][kb], acc[1][ch], 0, 0, 0);
        }

        if (t > 0) {
            // ---- poll all 256 (block,wave) flags: 64 lanes x 16B, throttled retry ----
            if (tid < NBLK) {
                const unsigned int* fp = flags + tid * 4;
                uint4v f;
                for (;;) {
                    asm volatile("global_load_dwordx4 %0, %1, off sc0 sc1\n\t"
                                 "s_waitcnt vmcnt(0)"
                                 : "=v"(f) : "v"(fp) : "memory");
                    if (f[0] >= (unsigned)t && f[1] >= (unsigned)t &&
                        f[2] >= (unsigned)t && f[3] >= (unsigned)t) break;
                    __builtin_amdgcn_s_sleep(1);   // ease L3 flag-line contention
                }
            }
            __syncthreads();

            // ---- h @ U: 16 back-to-back full-line L3 loads (block-major), ONE wait ----
            const unsigned short* rb = hbuf + pR * 32768 + arow * 8;
            short8 hreg[16];
#pragma unroll
            for (int kb = 0; kb < 16; ++kb)
                hload(hreg[kb], rb + (kb * 4 + rq) * 512);
            asm volatile("s_waitcnt vmcnt(0)" ::: "memory");
            __builtin_amdgcn_sched_barrier(0);
#pragma unroll
            for (int kb = 0; kb < 16; ++kb) {
                const int ch = kb & 3;
                acc[0][ch] = __builtin_amdgcn_mfma_f32_16x16x32_bf16(hreg[kb], ut[0][kb], acc[0][ch], 0, 0, 0);
                acc[1][ch] = __builtin_amdgcn_mfma_f32_16x16x32_bf16(hreg[kb], ut[1][kb], acc[1][ch], 0, 0, 0);
            }
        }
        // t == 0: h(-1) = 0, h@U contributes nothing -> skipped entirely.

        f32x4 gif = acc[0][0] + acc[0][1] + acc[0][2] + acc[0][3];
        f32x4 ggo = acc[1][0] + acc[1][1] + acc[1][2] + acc[1][3];
#pragma unroll
        for (int j = 0; j < 4; ++j) { gif[j] += bias0; ggo[j] += bias1; }

        // ---- gate exchange + nonlinearity ----
        f32x4 oif, ogo;
#pragma unroll
        for (int j = 0; j < 4; ++j) {
            oif[j] = __shfl_xor(gif[j], 8, 64);
            ogo[j] = __shfl_xor(ggo[j], 8, 64);
        }
        float hv[4];
#pragma unroll
        for (int j = 0; j < 4; ++j) {
            const float gi = up ? oif[j] : gif[j];
            const float gf = up ? gif[j] : oif[j];
            const float gg = up ? ogo[j] : ggo[j];
            const float go = up ? ggo[j] : ogo[j];
            const float iv = sigm(gi);
            const float fv = sigm(gf);
            const float gv = tanh_(gg);
            const float ov = sigm(go);
            const float cn = fv * cst[j] + iv * gv;
            cst[j] = cn;
            hv[j] = ov * tanh_(cn);
        }

        // ---------- publish h(t): LDS micro-transpose -> packed full-line store ----------
        if (t < SEQ - 1) {
            if (lower) {
#pragma unroll
                for (int j = 0; j < 4; ++j)
                    lds_w[(rq * 4 + j) * 8 + c16] = f2bf(hv[j]);
            }
            if (lane < 16) {
                short8 hpk = lds_s[w * 16 + lane];   // compiler inserts lgkmcnt before use
                hstore16(hpk, hbuf + pW * 32768 + bk * 512 + (size_t)(w * 16 + lane) * 8);
            }
            asm volatile("s_waitcnt vmcnt(0)" ::: "memory");  // h store acked at L3
            if (lane == 0)
                __hip_atomic_store(&flags[bk * 4 + w], (unsigned)(t + 1),
                                   __ATOMIC_RELAXED, __HIP_MEMORY_SCOPE_AGENT);
        }

        // ---------- output stores (off the critical path) ----------
        if (lower) {
#pragma unroll
            for (int j = 0; j < 4; ++j) {
                const int batch = w * 16 + rq * 4 + j;
                out[((size_t)t * BAT + batch) * NHID + hcol] = hv[j];
                if (t == SEQ - 1) {
                    hout[batch * NHID + hcol]  = hv[j];
                    cout_[batch * NHID + hcol] = cst[j];
                }
            }
        }

        // ---------- prefetch + convert x(t+1) (latency hides under next poll) ----------
        if (t < SEQ - 1) {
            const float* xr = x + ((size_t)(t + 1) * BAT + arow) * NINP + rq * 8;
#pragma unroll
            for (int kb = 0; kb < 8; ++kb) {
                f32x4 a0 = *(const f32x4*)(xr + kb * 32);
                f32x4 a1 = *(const f32x4*)(xr + kb * 32 + 4);
                short8 v;
#pragma unroll
                for (int j = 0; j < 4; ++j) {
                    v[j]     = (short)f2bf(a0[j]);
                    v[j + 4] = (short)f2bf(a1[j]);
                }
                xan[kb] = v;
            }
        }
    }
}

extern "C" void kernel_launch(void* const* d_in, const int* in_sizes, int n_in,
                              void* d_out, int out_size, void* d_ws, size_t ws_size,
                              hipStream_t stream) {
    (void)in_sizes; (void)n_in; (void)out_size; (void)ws_size;
    const float* x  = (const float*)d_in[0];
    const float* W  = (const float*)d_in[1];
    const float* U  = (const float*)d_in[2];
    const float* b  = (const float*)d_in[3];
    float* out = (float*)d_out;

    unsigned int*   flags = (unsigned int*)d_ws;
    unsigned short* hbuf  = (unsigned short*)((char*)d_ws + 4096);

    // zero flags (t=0 skips h@U, so hbuf needs no init; replay-safe)
    hipMemsetAsync(d_ws, 0, 4096, stream);
    hipLaunchKernelGGL(lstm_persistent, dim3(NBLK), dim3(NTHR), 0, stream,
                       x, W, U, b, out, hbuf, flags);
}

// Round 12
// 2766.470 us; speedup vs baseline: 1.3677x; 1.0932x over previous
//
#include <hip/hip_runtime.h>

#define NBLK 65      // block 0 = collector, 1..64 = workers
#define NTHR 256
#define SEQ  512
#define BAT  64
#define NINP 256
#define NHID 512
#define LDG  2048   // 4*NHID

typedef __attribute__((ext_vector_type(8))) short short8;
typedef __attribute__((ext_vector_type(4))) float f32x4;

static __device__ __forceinline__ unsigned short f2bf(float x) {
    return __builtin_bit_cast(unsigned short, (__bf16)x);
}
static __device__ __forceinline__ float sigm(float x)  { return 1.0f / (1.0f + __expf(-x)); }
static __device__ __forceinline__ float tanh_(float x) { return 2.0f / (1.0f + __expf(-2.0f * x)) - 1.0f; }

// L3-coherent 16B load / store, no implicit wait.
static __device__ __forceinline__ void hload(short8& d, const unsigned short* p) {
    asm volatile("global_load_dwordx4 %0, %1, off sc0 sc1" : "=v"(d) : "v"(p) : "memory");
}
static __device__ __forceinline__ void hstore16(short8 v, unsigned short* p) {
    asm volatile("global_store_dwordx4 %0, %1, off sc0 sc1" :: "v"(p), "v"(v) : "memory");
}

// d_ws layout:
//   [0, 16KB)      per-wave flags: slot (bk*4+w) at 64B stride -> 256 private lines
//   [16KB, 48KB)   epoch replicas: 8 lines at 4KB stride (workers poll bk&7)
//   [64KB, 192KB)  h double buffer, block-major: [parity][block][batch][8 cols] bf16
__global__ __launch_bounds__(NTHR, 1)
void lstm_persistent(const float* __restrict__ x, const float* __restrict__ W,
                     const float* __restrict__ U, const float* __restrict__ bias,
                     float* __restrict__ out, char* __restrict__ wsB)
{
    __shared__ short8 lds_s[4 * 16];   // per-wave 256B transpose staging (wave-private)

    const int tid  = threadIdx.x;
    const int w    = tid >> 6;
    const int lane = tid & 63;

    unsigned int* flags = (unsigned int*)wsB;

    // ================= collector block =================
    if (blockIdx.x == 0) {
        if (w != 0) return;            // only wave 0 collects
        for (int tc = 1; tc < SEQ; ++tc) {
            int gd = 1 << 22;          // fail-wrong, not hang
            for (;;) {
                unsigned f0, f1, f2, f3;
                const unsigned int* p0 = flags + lane * 16;
                const unsigned int* p1 = flags + (lane + 64) * 16;
                const unsigned int* p2 = flags + (lane + 128) * 16;
                const unsigned int* p3 = flags + (lane + 192) * 16;
                asm volatile(
                    "global_load_dword %0, %4, off sc0 sc1\n\t"
                    "global_load_dword %1, %5, off sc0 sc1\n\t"
                    "global_load_dword %2, %6, off sc0 sc1\n\t"
                    "global_load_dword %3, %7, off sc0 sc1\n\t"
                    "s_waitcnt vmcnt(0)"
                    : "=v"(f0), "=v"(f1), "=v"(f2), "=v"(f3)
                    : "v"(p0), "v"(p1), "v"(p2), "v"(p3) : "memory");
                const unsigned tt = (unsigned)tc;
                bool ok = f0 >= tt && f1 >= tt && f2 >= tt && f3 >= tt;
                if (__all(ok) || --gd == 0) break;
            }
            __builtin_amdgcn_sched_barrier(0);
            if (lane < 8) {            // publish epoch to 8 replicated lines
                unsigned int* ep = (unsigned int*)(wsB + 16384 + lane * 4096);
                unsigned val = (unsigned)tc;
                asm volatile("global_store_dword %0, %1, off sc0 sc1"
                             :: "v"(ep), "v"(val) : "memory");
            }
        }
        return;
    }

    // ================= worker blocks =================
    const int bk   = blockIdx.x - 1;
    const int c16  = lane & 15;
    const int rq   = lane >> 4;

    const int col0 = (c16 >> 3) * NHID + (c16 & 7) + bk * 8;   // i (c16<8) or f
    const int col1 = col0 + 2 * NHID;                           // g or o

    unsigned short* hbuf = (unsigned short*)(wsB + 65536);

    // ---- one-time: U,W slices into register B-fragments ----
    short8 ut[2][16];
#pragma unroll
    for (int kb = 0; kb < 16; ++kb) {
        const int k0 = kb * 32 + rq * 8;
        short8 v0, v1;
#pragma unroll
        for (int j = 0; j < 8; ++j) {
            v0[j] = (short)f2bf(U[(size_t)(k0 + j) * LDG + col0]);
            v1[j] = (short)f2bf(U[(size_t)(k0 + j) * LDG + col1]);
        }
        ut[0][kb] = v0; ut[1][kb] = v1;
    }
    short8 wt[2][8];
#pragma unroll
    for (int kb = 0; kb < 8; ++kb) {
        const int k0 = kb * 32 + rq * 8;
        short8 v0, v1;
#pragma unroll
        for (int j = 0; j < 8; ++j) {
            v0[j] = (short)f2bf(W[(size_t)(k0 + j) * LDG + col0]);
            v1[j] = (short)f2bf(W[(size_t)(k0 + j) * LDG + col1]);
        }
        wt[0][kb] = v0; wt[1][kb] = v1;
    }
    const float bias0 = bias[col0];
    const float bias1 = bias[col1];

    const int  arow  = w * 16 + c16;
    const bool lower = (c16 < 8);
    const bool up    = (c16 & 8);
    const int  hcol  = bk * 8 + (c16 & 7);
    float cst[4] = {0.f, 0.f, 0.f, 0.f};

    float* hout  = out + (size_t)SEQ * BAT * NHID;
    float* cout_ = hout + BAT * NHID;

    unsigned short* lds_w = (unsigned short*)&lds_s[w * 16];
    const unsigned int* epoch = (const unsigned int*)(wsB + 16384 + (bk & 7) * 4096);

    // ---- prologue: prefetch + convert x(0) fragments ----
    short8 xan[8];
    {
        const float* xr = x + (size_t)arow * NINP + rq * 8;
#pragma unroll
        for (int kb = 0; kb < 8; ++kb) {
            f32x4 a0 = *(const f32x4*)(xr + kb * 32);
            f32x4 a1 = *(const f32x4*)(xr + kb * 32 + 4);
            short8 v;
#pragma unroll
            for (int j = 0; j < 4; ++j) {
                v[j]     = (short)f2bf(a0[j]);
                v[j + 4] = (short)f2bf(a1[j]);
            }
            xan[kb] = v;
        }
    }

    for (int t = 0; t < SEQ; ++t) {
        const int pR = (t + 1) & 1;   // parity holding h(t-1)
        const int pW = t & 1;         // parity receiving h(t)

        // ---------- x @ W from prefetched register fragments ----------
        f32x4 acc[2][4];
#pragma unroll
        for (int nt = 0; nt < 2; ++nt)
#pragma unroll
            for (int ch = 0; ch < 4; ++ch) acc[nt][ch] = (f32x4){0.f, 0.f, 0.f, 0.f};
#pragma unroll
        for (int kb = 0; kb < 8; ++kb) {
            const int ch = kb & 3;
            acc[0][ch] = __builtin_amdgcn_mfma_f32_16x16x32_bf16(xan[kb], wt[0][kb], acc[0][ch], 0, 0, 0);
            acc[1][ch] = __builtin_amdgcn_mfma_f32_16x16x32_bf16(xan[kb], wt[1][kb], acc[1][ch], 0, 0, 0);
        }

        if (t > 0) {
            // ---- detect: poll the single epoch replica (broadcast read, 1 txn) ----
            {
                unsigned e;
                int gd = 1 << 22;
                do {
                    asm volatile("global_load_dword %0, %1, off sc0 sc1\n\t"
                                 "s_waitcnt vmcnt(0)"
                                 : "=v"(e) : "v"(epoch) : "memory");
                } while (e < (unsigned)t && --gd > 0);
            }
            __builtin_amdgcn_sched_barrier(0);

            // ---- h @ U: 16 full-line L3 loads (block-major), ONE wait ----
            const unsigned short* rb = hbuf + pR * 32768 + arow * 8;
            short8 hreg[16];
#pragma unroll
            for (int kb = 0; kb < 16; ++kb)
                hload(hreg[kb], rb + (kb * 4 + rq) * 512);
            asm volatile("s_waitcnt vmcnt(0)" ::: "memory");
            __builtin_amdgcn_sched_barrier(0);
#pragma unroll
            for (int kb = 0; kb < 16; ++kb) {
                const int ch = kb & 3;
                acc[0][ch] = __builtin_amdgcn_mfma_f32_16x16x32_bf16(hreg[kb], ut[0][kb], acc[0][ch], 0, 0, 0);
                acc[1][ch] = __builtin_amdgcn_mfma_f32_16x16x32_bf16(hreg[kb], ut[1][kb], acc[1][ch], 0, 0, 0);
            }
        }
        // t == 0: h(-1) = 0, h@U skipped.

        f32x4 gif = acc[0][0] + acc[0][1] + acc[0][2] + acc[0][3];
        f32x4 ggo = acc[1][0] + acc[1][1] + acc[1][2] + acc[1][3];
#pragma unroll
        for (int j = 0; j < 4; ++j) { gif[j] += bias0; ggo[j] += bias1; }

        // ---- gate exchange + nonlinearity ----
        f32x4 oif, ogo;
#pragma unroll
        for (int j = 0; j < 4; ++j) {
            oif[j] = __shfl_xor(gif[j], 8, 64);
            ogo[j] = __shfl_xor(ggo[j], 8, 64);
        }
        float hv[4];
#pragma unroll
        for (int j = 0; j < 4; ++j) {
            const float gi = up ? oif[j] : gif[j];
            const float gf = up ? gif[j] : oif[j];
            const float gg = up ? ogo[j] : ggo[j];
            const float go = up ? ggo[j] : ogo[j];
            const float iv = sigm(gi);
            const float fv = sigm(gf);
            const float gv = tanh_(gg);
            const float ov = sigm(go);
            const float cn = fv * cst[j] + iv * gv;
            cst[j] = cn;
            hv[j] = ov * tanh_(cn);
        }

        // ---------- publish h(t): LDS micro-transpose -> packed full-line store ----------
        if (t < SEQ - 1) {
            if (lower) {
#pragma unroll
                for (int j = 0; j < 4; ++j)
                    lds_w[(rq * 4 + j) * 8 + c16] = f2bf(hv[j]);
            }
            if (lane < 16) {
                short8 hpk = lds_s[w * 16 + lane];   // same-wave LDS, compiler lgkmcnt
                hstore16(hpk, hbuf + pW * 32768 + bk * 512 + (size_t)(w * 16 + lane) * 8);
            }
            asm volatile("s_waitcnt vmcnt(0)" ::: "memory");  // h store acked at L3
            if (lane == 0) {
                unsigned int* fp2 = flags + (bk * 4 + w) * 16;  // private 64B line
                unsigned int val = (unsigned)(t + 1);
                asm volatile("global_store_dword %0, %1, off sc0 sc1"
                             :: "v"(fp2), "v"(val) : "memory");
            }
        }

        // ---------- output stores (off the critical path) ----------
        if (lower) {
#pragma unroll
            for (int j = 0; j < 4; ++j) {
                const int batch = w * 16 + rq * 4 + j;
                out[((size_t)t * BAT + batch) * NHID + hcol] = hv[j];
                if (t == SEQ - 1) {
                    hout[batch * NHID + hcol]  = hv[j];
                    cout_[batch * NHID + hcol] = cst[j];
                }
            }
        }

        // ---------- prefetch + convert x(t+1) (latency hides under next poll) ----------
        if (t < SEQ - 1) {
            const float* xr = x + ((size_t)(t + 1) * BAT + arow) * NINP + rq * 8;
#pragma unroll
            for (int kb = 0; kb < 8; ++kb) {
                f32x4 a0 = *(const f32x4*)(xr + kb * 32);
                f32x4 a1 = *(const f32x4*)(xr + kb * 32 + 4);
                short8 v;
#pragma unroll
                for (int j = 0; j < 4; ++j) {
                    v[j]     = (short)f2bf(a0[j]);
                    v[j + 4] = (short)f2bf(a1[j]);
                }
                xan[kb] = v;
            }
        }
    }
}

extern "C" void kernel_launch(void* const* d_in, const int* in_sizes, int n_in,
                              void* d_out, int out_size, void* d_ws, size_t ws_size,
                              hipStream_t stream) {
    (void)in_sizes; (void)n_in; (void)out_size; (void)ws_size;
    const float* x  = (const float*)d_in[0];
    const float* W  = (const float*)d_in[1];
    const float* U  = (const float*)d_in[2];
    const float* b  = (const float*)d_in[3];
    float* out = (float*)d_out;

    // zero flags (16KB) + epoch replicas (to 48KB); h buffer needs no init (t=0 skips h@U)
    hipMemsetAsync(d_ws, 0, 65536, stream);
    hipLaunchKernelGGL(lstm_persistent, dim3(NBLK), dim3(NTHR), 0, stream,
                       x, W, U, b, out, (char*)d_ws);
}

// Round 15
// 2374.731 us; speedup vs baseline: 1.5934x; 1.1650x over previous
//
#include <hip/hip_runtime.h>

#define NBLK 64
#define NTHR 256
#define SEQ  512
#define BAT  64
#define NINP 256
#define NHID 512
#define LDG  2048   // 4*NHID

typedef __attribute__((ext_vector_type(8))) short short8;
typedef __attribute__((ext_vector_type(4))) float f32x4;

static __device__ __forceinline__ unsigned short f2bf(float x) {
    return __builtin_bit_cast(unsigned short, (__bf16)x);
}
static __device__ __forceinline__ float sigm(float x)  { return 1.0f / (1.0f + __expf(-x)); }
static __device__ __forceinline__ float tanh_(float x) { return 2.0f / (1.0f + __expf(-2.0f * x)) - 1.0f; }

// L3-coherent 16B load / store (bypass L1/L2), no implicit wait.
static __device__ __forceinline__ void hload(short8& d, const unsigned short* p) {
    asm volatile("global_load_dwordx4 %0, %1, off sc0 sc1" : "=v"(d) : "v"(p) : "memory");
}
static __device__ __forceinline__ void hstore16(short8 v, unsigned short* p) {
    asm volatile("global_store_dwordx4 %0, %1, off sc0 sc1" :: "v"(p), "v"(v) : "memory");
}
// plain 16B load (x prefetch), explicit issue, drained by a later vmcnt(0).
static __device__ __forceinline__ void pload(f32x4& d, const float* p) {
    asm volatile("global_load_dwordx4 %0, %1, off" : "=v"(d) : "v"(p) : "memory");
}

// d_ws: [0,4KB) block flags: 64 private 64B lines (dword at bk*16),
//       [4KB, 4KB+2*64KB) h double buffer, block-major: [parity][block][batch][8cols] bf16.
// Protocol per step (r6 semantics, minimum hops):
//   producer: h-store -> (xW shadow) -> vmcnt(0) -> __syncthreads -> ONE block flag store
//   consumer: wave0 polls 64 block flags (1 dword/lane) -> __syncthreads -> h loads
__global__ __launch_bounds__(NTHR, 1)
void lstm_persistent(const float* __restrict__ x, const float* __restrict__ W,
                     const float* __restrict__ U, const float* __restrict__ bias,
                     float* __restrict__ out, char* __restrict__ wsB)
{
    __shared__ short8 lds_s[4 * 16];   // per-wave 256B transpose staging (wave-private)

    const int bk   = blockIdx.x;
    const int tid  = threadIdx.x;
    const int w    = tid >> 6;
    const int lane = tid & 63;
    const int c16  = lane & 15;
    const int rq   = lane >> 4;

    unsigned int*   flags = (unsigned int*)wsB;
    unsigned short* hbuf  = (unsigned short*)(wsB + 4096);

    const int col0 = (c16 >> 3) * NHID + (c16 & 7) + bk * 8;   // i (c16<8) or f
    const int col1 = col0 + 2 * NHID;                           // g or o

    // ---- one-time: U,W slices into register B-fragments ----
    short8 ut[2][16];
#pragma unroll
    for (int kb = 0; kb < 16; ++kb) {
        const int k0 = kb * 32 + rq * 8;
        short8 v0, v1;
#pragma unroll
        for (int j = 0; j < 8; ++j) {
            v0[j] = (short)f2bf(U[(size_t)(k0 + j) * LDG + col0]);
            v1[j] = (short)f2bf(U[(size_t)(k0 + j) * LDG + col1]);
        }
        ut[0][kb] = v0; ut[1][kb] = v1;
    }
    short8 wt[2][8];
#pragma unroll
    for (int kb = 0; kb < 8; ++kb) {
        const int k0 = kb * 32 + rq * 8;
        short8 v0, v1;
#pragma unroll
        for (int j = 0; j < 8; ++j) {
            v0[j] = (short)f2bf(W[(size_t)(k0 + j) * LDG + col0]);
            v1[j] = (short)f2bf(W[(size_t)(k0 + j) * LDG + col1]);
        }
        wt[0][kb] = v0; wt[1][kb] = v1;
    }
    const float bias0 = bias[col0];
    const float bias1 = bias[col1];

    const int  arow  = w * 16 + c16;
    const bool lower = (c16 < 8);
    const bool up    = (c16 & 8);
    const int  hcol  = bk * 8 + (c16 & 7);
    float cst[4] = {0.f, 0.f, 0.f, 0.f};

    float* hout  = out + (size_t)SEQ * BAT * NHID;
    float* cout_ = hout + BAT * NHID;

    unsigned short* lds_w = (unsigned short*)&lds_s[w * 16];

    // ---- prologue: x(0) load+convert, xW(0) into accA ----
    f32x4 accA[2][4];
#pragma unroll
    for (int nt = 0; nt < 2; ++nt)
#pragma unroll
        for (int ch = 0; ch < 4; ++ch) accA[nt][ch] = (f32x4){0.f, 0.f, 0.f, 0.f};
    {
        const float* xr = x + (size_t)arow * NINP + rq * 8;
#pragma unroll
        for (int kb = 0; kb < 8; ++kb) {
            f32x4 a0 = *(const f32x4*)(xr + kb * 32);
            f32x4 a1 = *(const f32x4*)(xr + kb * 32 + 4);
            short8 v;
#pragma unroll
            for (int j = 0; j < 4; ++j) {
                v[j]     = (short)f2bf(a0[j]);
                v[j + 4] = (short)f2bf(a1[j]);
            }
            const int ch = kb & 3;
            accA[0][ch] = __builtin_amdgcn_mfma_f32_16x16x32_bf16(v, wt[0][kb], accA[0][ch], 0, 0, 0);
            accA[1][ch] = __builtin_amdgcn_mfma_f32_16x16x32_bf16(v, wt[1][kb], accA[1][ch], 0, 0, 0);
        }
    }

    f32x4 xraw[16];   // raw x(t+1), issued at step top, converted in the ack shadow

    for (int t = 0; t < SEQ; ++t) {
        const int pR = (t + 1) & 1;   // parity holding h(t-1)
        const int pW = t & 1;         // parity receiving h(t)

        // ---- step top: issue x(t+1) raw loads (in flight across poll + h-load) ----
        if (t < SEQ - 1) {
            const float* xr = x + ((size_t)(t + 1) * BAT + arow) * NINP + rq * 8;
#pragma unroll
            for (int kb = 0; kb < 8; ++kb) {
                pload(xraw[2 * kb],     xr + kb * 32);
                pload(xraw[2 * kb + 1], xr + kb * 32 + 4);
            }
        }

        if (t > 0) {
            // ---- detect: wave 0 polls the 64 block flags (1 dword/lane) ----
            if (w == 0) {
                const unsigned int* fp = flags + lane * 16;
                unsigned f;
                do {
                    asm volatile("global_load_dword %0, %1, off sc0 sc1\n\t"
                                 "s_waitcnt vmcnt(0)"
                                 : "=v"(f) : "v"(fp) : "memory");
                } while (!__all(f >= (unsigned)t));
            }
            __syncthreads();

            // ---- h @ U: 16 full-line L3 loads, ONE wait (also drains xraw) ----
            const unsigned short* rb = hbuf + pR * 32768 + arow * 8;
            short8 hreg[16];
#pragma unroll
            for (int kb = 0; kb < 16; ++kb)
                hload(hreg[kb], rb + (kb * 4 + rq) * 512);
            asm volatile("s_waitcnt vmcnt(0)" ::: "memory");
            __builtin_amdgcn_sched_barrier(0);
#pragma unroll
            for (int kb = 0; kb < 16; ++kb) {
                const int ch = kb & 3;
                accA[0][ch] = __builtin_amdgcn_mfma_f32_16x16x32_bf16(hreg[kb], ut[0][kb], accA[0][ch], 0, 0, 0);
                accA[1][ch] = __builtin_amdgcn_mfma_f32_16x16x32_bf16(hreg[kb], ut[1][kb], accA[1][ch], 0, 0, 0);
            }
        }
        // t == 0: h(-1)=0, hU skipped; accA holds xW(0) from prologue.

        f32x4 gif = accA[0][0] + accA[0][1] + accA[0][2] + accA[0][3];
        f32x4 ggo = accA[1][0] + accA[1][1] + accA[1][2] + accA[1][3];
#pragma unroll
        for (int j = 0; j < 4; ++j) { gif[j] += bias0; ggo[j] += bias1; }

        // ---- gate exchange + nonlinearity ----
        f32x4 oif, ogo;
#pragma unroll
        for (int j = 0; j < 4; ++j) {
            oif[j] = __shfl_xor(gif[j], 8, 64);
            ogo[j] = __shfl_xor(ggo[j], 8, 64);
        }
        float hv[4];
#pragma unroll
        for (int j = 0; j < 4; ++j) {
            const float gi = up ? oif[j] : gif[j];
            const float gf = up ? gif[j] : oif[j];
            const float gg = up ? ogo[j] : ggo[j];
            const float go = up ? ggo[j] : ogo[j];
            const float iv = sigm(gi);
            const float fv = sigm(gf);
            const float gv = tanh_(gg);
            const float ov = sigm(go);
            const float cn = fv * cst[j] + iv * gv;
            cst[j] = cn;
            hv[j] = ov * tanh_(cn);
        }

        if (t < SEQ - 1) {
            // ---- publish: LDS micro-transpose -> packed full-line h store ----
            if (lower) {
#pragma unroll
                for (int j = 0; j < 4; ++j)
                    lds_w[(rq * 4 + j) * 8 + c16] = f2bf(hv[j]);
            }
            if (lane < 16) {
                short8 hpk = lds_s[w * 16 + lane];   // compiler inserts lgkmcnt
                hstore16(hpk, hbuf + pW * 32768 + bk * 512 + (size_t)(w * 16 + lane) * 8);
            }
            __builtin_amdgcn_sched_barrier(0);

            // ---- FIX (r14): at t==0 nothing has drained the xraw loads yet ----
            if (t == 0) {
                asm volatile("s_waitcnt vmcnt(0)" ::: "memory");
            }
            __builtin_amdgcn_sched_barrier(0);
            // volatile pass-through: pins the conversions AFTER the preceding
            // waitcnt at every t (register-only VALU would otherwise be free
            // to hoist above the asm waitcnt — rule #18 class).
#pragma unroll
            for (int i = 0; i < 16; ++i)
                asm volatile("" : "+v"(xraw[i]));

            // ---- ack shadow: zero accA, convert x(t+1), xW(t+1) MFMAs ----
#pragma unroll
            for (int nt = 0; nt < 2; ++nt)
#pragma unroll
                for (int ch = 0; ch < 4; ++ch) accA[nt][ch] = (f32x4){0.f, 0.f, 0.f, 0.f};
#pragma unroll
            for (int kb = 0; kb < 8; ++kb) {
                short8 v;
#pragma unroll
                for (int j = 0; j < 4; ++j) {
                    v[j]     = (short)f2bf(xraw[2 * kb][j]);
                    v[j + 4] = (short)f2bf(xraw[2 * kb + 1][j]);
                }
                const int ch = kb & 3;
                accA[0][ch] = __builtin_amdgcn_mfma_f32_16x16x32_bf16(v, wt[0][kb], accA[0][ch], 0, 0, 0);
                accA[1][ch] = __builtin_amdgcn_mfma_f32_16x16x32_bf16(v, wt[1][kb], accA[1][ch], 0, 0, 0);
            }
            __builtin_amdgcn_sched_barrier(0);

            // ---- retire h store; block-aggregate; ONE flag store per block ----
            asm volatile("s_waitcnt vmcnt(0)" ::: "memory");
            __syncthreads();
            if (tid == 0) {
                unsigned int* fp2 = flags + bk * 16;   // private 64B line
                unsigned int val = (unsigned)(t + 1);
                asm volatile("global_store_dword %0, %1, off sc0 sc1"
                             :: "v"(fp2), "v"(val) : "memory");
            }

            // ---- out stores (off path; drain under next step's vmcnt) ----
            if (lower) {
#pragma unroll
                for (int j = 0; j < 4; ++j) {
                    const int batch = w * 16 + rq * 4 + j;
                    out[((size_t)t * BAT + batch) * NHID + hcol] = hv[j];
                }
            }
        } else {
            // tail step: final outputs only
            if (lower) {
#pragma unroll
                for (int j = 0; j < 4; ++j) {
                    const int batch = w * 16 + rq * 4 + j;
                    out[((size_t)t * BAT + batch) * NHID + hcol] = hv[j];
                    hout[batch * NHID + hcol]  = hv[j];
                    cout_[batch * NHID + hcol] = cst[j];
                }
            }
        }
    }
}

extern "C" void kernel_launch(void* const* d_in, const int* in_sizes, int n_in,
                              void* d_out, int out_size, void* d_ws, size_t ws_size,
                              hipStream_t stream) {
    (void)in_sizes; (void)n_in; (void)out_size; (void)ws_size;
    const float* x  = (const float*)d_in[0];
    const float* W  = (const float*)d_in[1];
    const float* U  = (const float*)d_in[2];
    const float* b  = (const float*)d_in[3];
    float* out = (float*)d_out;

    // zero block flags (4KB); hbuf needs no init (t=0 skips hU); replay-safe
    (void)hipMemsetAsync(d_ws, 0, 4096, stream);
    hipLaunchKernelGGL(lstm_persistent, dim3(NBLK), dim3(NTHR), 0, stream,
                       x, W, U, b, out, (char*)d_ws);
}

// Round 16
// 2230.025 us; speedup vs baseline: 1.6968x; 1.0649x over previous
//
#include <hip/hip_runtime.h>

#define NBLK 64
#define NTHR 256
#define SEQ  512
#define BAT  64
#define NINP 256
#define NHID 512
#define LDG  2048   // 4*NHID

typedef __attribute__((ext_vector_type(8))) short short8;
typedef __attribute__((ext_vector_type(4))) float f32x4;

static __device__ __forceinline__ unsigned short f2bf(float x) {
    return __builtin_bit_cast(unsigned short, (__bf16)x);
}
static __device__ __forceinline__ float sigm(float x)  { return 1.0f / (1.0f + __expf(-x)); }
static __device__ __forceinline__ float tanh_(float x) { return 2.0f / (1.0f + __expf(-2.0f * x)) - 1.0f; }

// L3-coherent 16B load / store (bypass L1/L2), no implicit wait.
static __device__ __forceinline__ void hload(short8& d, const unsigned short* p) {
    asm volatile("global_load_dwordx4 %0, %1, off sc0 sc1" : "=v"(d) : "v"(p) : "memory");
}
static __device__ __forceinline__ void hstore16(short8 v, unsigned short* p) {
    asm volatile("global_store_dwordx4 %0, %1, off sc0 sc1" :: "v"(p), "v"(v) : "memory");
}
// plain 16B load (x prefetch), explicit issue, drained by a later vmcnt(0).
static __device__ __forceinline__ void pload(f32x4& d, const float* p) {
    asm volatile("global_load_dwordx4 %0, %1, off" : "=v"(d) : "v"(p) : "memory");
}

// d_ws: [0,16KB) per-(block,wave) flags: 256 private 64B lines (dword at (bk*4+w)*16),
//       [16KB, +2*64KB) h double buffer, block-major: [parity][block][batch][8cols] bf16.
//
// WAVE-DECOUPLED sync: wave w of block b writes batch rows [16w,16w+16) and its
// readers are exactly wave w of every block. So sync is 4 independent all-to-alls:
//   producer wave: h-store -> xW shadow -> vmcnt(0) -> OWN flag store  (no barrier)
//   consumer wave: poll the 64 wave-w flags (lane=block)               (no barrier)
__global__ __launch_bounds__(NTHR, 1)
void lstm_persistent(const float* __restrict__ x, const float* __restrict__ W,
                     const float* __restrict__ U, const float* __restrict__ bias,
                     float* __restrict__ out, char* __restrict__ wsB)
{
    __shared__ short8 lds_s[4 * 16];   // per-wave 256B transpose staging (wave-private)

    const int bk   = blockIdx.x;
    const int tid  = threadIdx.x;
    const int w    = tid >> 6;
    const int lane = tid & 63;
    const int c16  = lane & 15;
    const int rq   = lane >> 4;

    unsigned int*   flags = (unsigned int*)wsB;
    unsigned short* hbuf  = (unsigned short*)(wsB + 16384);

    const int col0 = (c16 >> 3) * NHID + (c16 & 7) + bk * 8;   // i (c16<8) or f
    const int col1 = col0 + 2 * NHID;                           // g or o

    // ---- one-time: U,W slices into register B-fragments ----
    short8 ut[2][16];
#pragma unroll
    for (int kb = 0; kb < 16; ++kb) {
        const int k0 = kb * 32 + rq * 8;
        short8 v0, v1;
#pragma unroll
        for (int j = 0; j < 8; ++j) {
            v0[j] = (short)f2bf(U[(size_t)(k0 + j) * LDG + col0]);
            v1[j] = (short)f2bf(U[(size_t)(k0 + j) * LDG + col1]);
        }
        ut[0][kb] = v0; ut[1][kb] = v1;
    }
    short8 wt[2][8];
#pragma unroll
    for (int kb = 0; kb < 8; ++kb) {
        const int k0 = kb * 32 + rq * 8;
        short8 v0, v1;
#pragma unroll
        for (int j = 0; j < 8; ++j) {
            v0[j] = (short)f2bf(W[(size_t)(k0 + j) * LDG + col0]);
            v1[j] = (short)f2bf(W[(size_t)(k0 + j) * LDG + col1]);
        }
        wt[0][kb] = v0; wt[1][kb] = v1;
    }
    const float bias0 = bias[col0];
    const float bias1 = bias[col1];

    const int  arow  = w * 16 + c16;
    const bool lower = (c16 < 8);
    const bool up    = (c16 & 8);
    const int  hcol  = bk * 8 + (c16 & 7);
    float cst[4] = {0.f, 0.f, 0.f, 0.f};

    float* hout  = out + (size_t)SEQ * BAT * NHID;
    float* cout_ = hout + BAT * NHID;

    unsigned short* lds_w = (unsigned short*)&lds_s[w * 16];

    // ---- prologue: x(0) load+convert, xW(0) into accA ----
    f32x4 accA[2][4];
#pragma unroll
    for (int nt = 0; nt < 2; ++nt)
#pragma unroll
        for (int ch = 0; ch < 4; ++ch) accA[nt][ch] = (f32x4){0.f, 0.f, 0.f, 0.f};
    {
        const float* xr = x + (size_t)arow * NINP + rq * 8;
#pragma unroll
        for (int kb = 0; kb < 8; ++kb) {
            f32x4 a0 = *(const f32x4*)(xr + kb * 32);
            f32x4 a1 = *(const f32x4*)(xr + kb * 32 + 4);
            short8 v;
#pragma unroll
            for (int j = 0; j < 4; ++j) {
                v[j]     = (short)f2bf(a0[j]);
                v[j + 4] = (short)f2bf(a1[j]);
            }
            const int ch = kb & 3;
            accA[0][ch] = __builtin_amdgcn_mfma_f32_16x16x32_bf16(v, wt[0][kb], accA[0][ch], 0, 0, 0);
            accA[1][ch] = __builtin_amdgcn_mfma_f32_16x16x32_bf16(v, wt[1][kb], accA[1][ch], 0, 0, 0);
        }
    }

    f32x4 xraw[16];   // raw x(t+1), issued at step top, converted in the ack shadow

    for (int t = 0; t < SEQ; ++t) {
        const int pR = (t + 1) & 1;   // parity holding h(t-1)
        const int pW = t & 1;         // parity receiving h(t)

        // ---- step top: issue x(t+1) raw loads (in flight across poll + h-load) ----
        if (t < SEQ - 1) {
            const float* xr = x + ((size_t)(t + 1) * BAT + arow) * NINP + rq * 8;
#pragma unroll
            for (int kb = 0; kb < 8; ++kb) {
                pload(xraw[2 * kb],     xr + kb * 32);
                pload(xraw[2 * kb + 1], xr + kb * 32 + 4);
            }
        }

        if (t > 0) {
            // ---- detect: EVERY wave polls the 64 wave-w flags (lane = block) ----
            {
                const unsigned int* fp = flags + (lane * 4 + w) * 16;
                unsigned f;
                do {
                    asm volatile("global_load_dword %0, %1, off sc0 sc1\n\t"
                                 "s_waitcnt vmcnt(0)"
                                 : "=v"(f) : "v"(fp) : "memory");
                } while (!__all(f >= (unsigned)t));
            }
            __builtin_amdgcn_sched_barrier(0);

            // ---- h @ U: 16 full-line L3 loads, ONE wait (also drains xraw) ----
            const unsigned short* rb = hbuf + pR * 32768 + arow * 8;
            short8 hreg[16];
#pragma unroll
            for (int kb = 0; kb < 16; ++kb)
                hload(hreg[kb], rb + (kb * 4 + rq) * 512);
            asm volatile("s_waitcnt vmcnt(0)" ::: "memory");
            __builtin_amdgcn_sched_barrier(0);
#pragma unroll
            for (int kb = 0; kb < 16; ++kb) {
                const int ch = kb & 3;
                accA[0][ch] = __builtin_amdgcn_mfma_f32_16x16x32_bf16(hreg[kb], ut[0][kb], accA[0][ch], 0, 0, 0);
                accA[1][ch] = __builtin_amdgcn_mfma_f32_16x16x32_bf16(hreg[kb], ut[1][kb], accA[1][ch], 0, 0, 0);
            }
        }
        // t == 0: h(-1)=0, hU skipped; accA holds xW(0) from prologue.

        f32x4 gif = accA[0][0] + accA[0][1] + accA[0][2] + accA[0][3];
        f32x4 ggo = accA[1][0] + accA[1][1] + accA[1][2] + accA[1][3];
#pragma unroll
        for (int j = 0; j < 4; ++j) { gif[j] += bias0; ggo[j] += bias1; }

        // ---- gate exchange + nonlinearity ----
        f32x4 oif, ogo;
#pragma unroll
        for (int j = 0; j < 4; ++j) {
            oif[j] = __shfl_xor(gif[j], 8, 64);
            ogo[j] = __shfl_xor(ggo[j], 8, 64);
        }
        float hv[4];
#pragma unroll
        for (int j = 0; j < 4; ++j) {
            const float gi = up ? oif[j] : gif[j];
            const float gf = up ? gif[j] : oif[j];
            const float gg = up ? ogo[j] : ogo[j] * 0.0f + (up ? ogo[j] : ggo[j]); // placeholder removed below
            const float go = 0.0f;
            (void)gg; (void)go;
            break;
        }
        // (rewritten cleanly below — see gates)
#pragma unroll
        for (int j = 0; j < 4; ++j) {
            const float gi = up ? oif[j] : gif[j];
            const float gf = up ? gif[j] : oif[j];
            const float gg = up ? ogo[j] : ggo[j];
            const float go = up ? ggo[j] : ogo[j];
            const float iv = sigm(gi);
            const float fv = sigm(gf);
            const float gv = tanh_(gg);
            const float ov = sigm(go);
            const float cn = fv * cst[j] + iv * gv;
            cst[j] = cn;
            hv[j] = ov * tanh_(cn);
        }

        if (t < SEQ - 1) {
            // ---- publish: LDS micro-transpose -> packed full-line h store ----
            if (lower) {
#pragma unroll
                for (int j = 0; j < 4; ++j)
                    lds_w[(rq * 4 + j) * 8 + c16] = f2bf(hv[j]);
            }
            if (lane < 16) {
                short8 hpk = lds_s[w * 16 + lane];   // same-wave LDS, compiler lgkmcnt
                hstore16(hpk, hbuf + pW * 32768 + bk * 512 + (size_t)(w * 16 + lane) * 8);
            }
            __builtin_amdgcn_sched_barrier(0);

            // ---- t==0: nothing has drained the xraw loads yet ----
            if (t == 0) {
                asm volatile("s_waitcnt vmcnt(0)" ::: "memory");
            }
            __builtin_amdgcn_sched_barrier(0);
            // volatile pass-through pins conversions after the preceding waitcnt
#pragma unroll
            for (int i = 0; i < 16; ++i)
                asm volatile("" : "+v"(xraw[i]));

            // ---- ack shadow: zero accA, convert x(t+1), xW(t+1) MFMAs ----
#pragma unroll
            for (int nt = 0; nt < 2; ++nt)
#pragma unroll
                for (int ch = 0; ch < 4; ++ch) accA[nt][ch] = (f32x4){0.f, 0.f, 0.f, 0.f};
#pragma unroll
            for (int kb = 0; kb < 8; ++kb) {
                short8 v;
#pragma unroll
                for (int j = 0; j < 4; ++j) {
                    v[j]     = (short)f2bf(xraw[2 * kb][j]);
                    v[j + 4] = (short)f2bf(xraw[2 * kb + 1][j]);
                }
                const int ch = kb & 3;
                accA[0][ch] = __builtin_amdgcn_mfma_f32_16x16x32_bf16(v, wt[0][kb], accA[0][ch], 0, 0, 0);
                accA[1][ch] = __builtin_amdgcn_mfma_f32_16x16x32_bf16(v, wt[1][kb], accA[1][ch], 0, 0, 0);
            }
            __builtin_amdgcn_sched_barrier(0);

            // ---- retire this wave's h store; publish OWN flag (no barrier) ----
            asm volatile("s_waitcnt vmcnt(0)" ::: "memory");
            if (lane == 0) {
                unsigned int* fp2 = flags + (bk * 4 + w) * 16;   // private 64B line
                unsigned int val = (unsigned)(t + 1);
                asm volatile("global_store_dword %0, %1, off sc0 sc1"
                             :: "v"(fp2), "v"(val) : "memory");
            }

            // ---- out stores (off path; drain under next step's vmcnt) ----
            if (lower) {
#pragma unroll
                for (int j = 0; j < 4; ++j) {
                    const int batch = w * 16 + rq * 4 + j;
                    out[((size_t)t * BAT + batch) * NHID + hcol] = hv[j];
                }
            }
        } else {
            // tail step: final outputs only
            if (lower) {
#pragma unroll
                for (int j = 0; j < 4; ++j) {
                    const int batch = w * 16 + rq * 4 + j;
                    out[((size_t)t * BAT + batch) * NHID + hcol] = hv[j];
                    hout[batch * NHID + hcol]  = hv[j];
                    cout_[batch * NHID + hcol] = cst[j];
                }
            }
        }
    }
}

extern "C" void kernel_launch(void* const* d_in, const int* in_sizes, int n_in,
                              void* d_out, int out_size, void* d_ws, size_t ws_size,
                              hipStream_t stream) {
    (void)in_sizes; (void)n_in; (void)out_size; (void)ws_size;
    const float* x  = (const float*)d_in[0];
    const float* W  = (const float*)d_in[1];
    const float* U  = (const float*)d_in[2];
    const float* b  = (const float*)d_in[3];
    float* out = (float*)d_out;

    // zero per-(block,wave) flags (16KB); hbuf needs no init; replay-safe
    (void)hipMemsetAsync(d_ws, 0, 16384, stream);
    hipLaunchKernelGGL(lstm_persistent, dim3(NBLK), dim3(NTHR), 0, stream,
                       x, W, U, b, out, (char*)d_ws);
}